// Round 20
// baseline (151.895 us; speedup 1.0000x reference)
//
#include <hip/hip_runtime.h>

// ---- types ----
typedef __bf16 bf16x8 __attribute__((ext_vector_type(8)));
typedef float f32x4 __attribute__((ext_vector_type(4)));
typedef float f32x16 __attribute__((ext_vector_type(16)));
typedef unsigned short ushort8 __attribute__((ext_vector_type(8)));
typedef unsigned short ushort4v __attribute__((ext_vector_type(4)));
typedef unsigned int uint4v __attribute__((ext_vector_type(4)));

union Frag {
  ushort8 u;
  bf16x8 b;
  uint4v w;
};

__device__ __forceinline__ unsigned short f2bf(float f) {
  unsigned int u = __float_as_uint(f);
  u += 0x7fffu + ((u >> 16) & 1u);   // RNE; inputs are finite
  return (unsigned short)(u >> 16);
}

__device__ __forceinline__ f32x4 fz4() {
  f32x4 v; v[0] = 0.f; v[1] = 0.f; v[2] = 0.f; v[3] = 0.f; return v;
}

__device__ __forceinline__ f32x16 fz16() {
  f32x16 v;
#pragma unroll
  for (int i = 0; i < 16; ++i) v[i] = 0.f;
  return v;
}

#define MFMA16(a, b, c) __builtin_amdgcn_mfma_f32_16x16x32_bf16(a, b, c, 0, 0, 0)
#define MFMA32(a, b, c) __builtin_amdgcn_mfma_f32_32x32x16_bf16(a, b, c, 0, 0, 0)

#define LOG2E 1.4426950408889634f

// Sizes: B=8, C=256, N=4096 (64x64), IC=128. OUTPUT FP32 (32 MiB).
// ws (ushort): wcatS 98304 | wmbS 32768 | theta 8*524288 | phiS 8*524288 | vS 8*524288
// theta: linear [n][128], PRE-SCALED by log2(e)  (softmax runs in exp2 domain)
// phiS swizzled (per batch): addr = t*4096 + kc*512 + lane*8 + e
// vS swizzled (per batch):  addr = t*4096 + t8*512 + lane*8 + e
// wcatS fragment-swizzled: element (row,col) -> ((row>>4)*8 + (col>>5))*512 +
//   (((col>>3)&3)*16 + (row&15))*8 + (col&7)    [rows 0-127 wt | 128-255 wp | 256-383 wg]
// wmbS  fragment-swizzled: ((row>>4)*4 + (col>>5))*512 + (((col>>3)&3)*16+(row&15))*8+(col&7)
// attn output out_nm (aliases theta): phiS-style swizzle -> k_mask coalesced.

// ---------------- prep: weights fp32 -> bf16, fragment-swizzled --------------
__global__ void k_prep(const float* __restrict__ wg, const float* __restrict__ wt,
                       const float* __restrict__ wp, const float* __restrict__ wm,
                       unsigned short* __restrict__ wcatS, unsigned short* __restrict__ wmbS) {
  int t = blockIdx.x * 256 + threadIdx.x;
  if (t < 98304) {
    int row = t >> 8, col = t & 255;
    const float* src = (row < 128) ? wt : ((row < 256) ? wp : wg);
    unsigned short v = f2bf(src[(row & 127) * 256 + col]);
    int R = row >> 4, lr = row & 15, kc = col >> 5, lg = (col >> 3) & 3, e = col & 7;
    wcatS[((R * 8 + kc) * 64 + lg * 16 + lr) * 8 + e] = v;
  }
  if (t < 32768) {
    int row = t >> 7, col = t & 127;
    unsigned short v = f2bf(wm[t]);
    int R = row >> 4, lr = row & 15, kc = col >> 5, lg = (col >> 3) & 3, e = col & 7;
    wmbS[((R * 4 + kc) * 64 + lg * 16 + lr) * 8 + e] = v;
  }
}

// ---- shared staging: x[bx][c][pt0..pt0+64) -> xb[p][c] bf16, row stride 264 ----
__device__ __forceinline__ void stage_x(const float* __restrict__ x, int bx, int pt0,
                                        unsigned short* xb, int tid) {
  int c0 = (tid >> 2) * 4;
  int psub = (tid & 3) * 16;
  const float* xbase = x + (size_t)bx * 256 * 4096 + pt0;
  for (int ppc = 0; ppc < 4; ++ppc) {
    int p0 = psub + ppc * 4;
    f32x4 r0 = *(const f32x4*)(xbase + (size_t)(c0 + 0) * 4096 + p0);
    f32x4 r1 = *(const f32x4*)(xbase + (size_t)(c0 + 1) * 4096 + p0);
    f32x4 r2 = *(const f32x4*)(xbase + (size_t)(c0 + 2) * 4096 + p0);
    f32x4 r3 = *(const f32x4*)(xbase + (size_t)(c0 + 3) * 4096 + p0);
    for (int e = 0; e < 4; ++e) {
      ushort4v wv;
      wv[0] = f2bf(r0[e]); wv[1] = f2bf(r1[e]); wv[2] = f2bf(r2[e]); wv[3] = f2bf(r3[e]);
      *(ushort4v*)&xb[(p0 + e) * 264 + c0] = wv;
    }
  }
}

// ---------------- fused projections: theta (scaled), phiS, vS ----------------
__global__ __launch_bounds__(256, 2) void k_proj(
    const float* __restrict__ x, const unsigned short* __restrict__ wcatS,
    const float* __restrict__ bt, const float* __restrict__ bp,
    const float* __restrict__ bg,
    unsigned short* __restrict__ theta, unsigned short* __restrict__ phiS,
    unsigned short* __restrict__ vS) {
  __shared__ unsigned short xb[64 * 264];
  int gb = blockIdx.x >> 6;
  size_t ob_off = (size_t)gb * 524288;
  int pt0 = (blockIdx.x & 63) << 6;
  int tid = threadIdx.x;
  stage_x(x, gb, pt0, xb, tid);
  __syncthreads();
  int l = tid & 63, w = tid >> 6, lr = l & 15, lg = l >> 4;
  int l8 = l * 8;
  int obase = w * 64;
  f32x4 acc[4][4];
  f32x4 accg[8];
  for (int i = 0; i < 4; ++i) for (int j = 0; j < 4; ++j) acc[i][j] = fz4();
  for (int i = 0; i < 8; ++i) accg[i] = fz4();
  for (int kc = 0; kc < 8; ++kc) {
    int ko = kc * 32 + 8 * lg;
    Frag wa[4], xq[4];
    for (int ot = 0; ot < 4; ++ot)
      wa[ot].u = *(const ushort8*)(wcatS + ((w * 4 + ot) * 8 + kc) * 512 + l8);
    for (int pt = 0; pt < 4; ++pt)
      xq[pt].u = *(const ushort8*)&xb[(pt * 16 + lr) * 264 + ko];
    for (int ot = 0; ot < 4; ++ot)
      for (int pt = 0; pt < 4; ++pt)
        acc[ot][pt] = MFMA16(wa[ot].b, xq[pt].b, acc[ot][pt]);
    for (int ot = 0; ot < 8; ++ot) {
      Frag wb;
      wb.u = *(const ushort8*)(wcatS + ((16 + ot) * 8 + kc) * 512 + l8);
      accg[ot] = MFMA16(xq[w].b, wb.b, accg[ot]);
    }
  }
  // epilogue theta/phi
  for (int ot = 0; ot < 4; ++ot) {
    int o0 = obase + ot * 16 + 4 * lg;
    float bias[4];
    for (int j = 0; j < 4; ++j) bias[j] = (o0 < 128) ? bt[o0 + j] : bp[o0 + j - 128];
    for (int pt = 0; pt < 4; ++pt) {
      int n = pt0 + pt * 16 + lr;
      ushort4v wv;
      if (o0 < 128) {
        for (int j = 0; j < 4; ++j) {
          float v = acc[ot][pt][j] + bias[j];
          wv[j] = f2bf(v > 0.f ? v * LOG2E : 0.f);   // exp2-domain Q
        }
        *(ushort4v*)(theta + ob_off + (size_t)n * 128 + o0) = wv;
      } else {
        for (int j = 0; j < 4; ++j) {
          float v = acc[ot][pt][j] + bias[j];
          wv[j] = f2bf(v > 0.f ? v : 0.f);
        }
        int oc = o0 - 128;
        size_t a = (size_t)(n >> 5) * 4096 + (size_t)(oc >> 4) * 512 +
                   (size_t)((oc >> 3) & 1) * 256 + (size_t)(n & 31) * 8 + (oc & 7);
        *(ushort4v*)(phiS + ob_off + a) = wv;
      }
    }
  }
  // epilogue g
  for (int ot = 0; ot < 8; ++ot) {
    int o = ot * 16 + lr;
    float bias = bg[o];
    int n0 = pt0 + w * 16 + 4 * lg;
    ushort4v wv;
    for (int j = 0; j < 4; ++j) {
      float v = accg[ot][j] + bias;
      wv[j] = f2bf(v > 0.f ? v : 0.f);
    }
    size_t a = (size_t)(n0 >> 5) * 4096 +
               (size_t)((o >> 5) * 2 + ((n0 >> 4) & 1)) * 512 +
               (size_t)((((n0 >> 3) & 1) << 5) | (o & 31)) * 8 + (n0 & 7);
    *(ushort4v*)(vS + ob_off + a) = wv;
  }
}

// ---------------- fused flash attention (r14 structure + T5 setprio) --------
// A/B vs r19: ONLY change is s_setprio(1)/(0) around the two MFMA clusters.
// Mechanism (m191): no in-loop barriers -> resident waves drift to different
// phases; setprio lets the scheduler favor the MFMA-entering wave.
__global__ __launch_bounds__(256, 2) void k_attn(
    const unsigned short* __restrict__ theta, const unsigned short* __restrict__ phiS,
    const unsigned short* __restrict__ vS, unsigned short* __restrict__ out_nm) {
  __shared__ float osum[64][132];
  __shared__ float mls[4][32][2];
  int bid = blockIdx.x;
  int b = bid & 7;                    // XCD-aware: batch per XCD
  int bq0 = (bid >> 3) << 6;          // 64 q-rows per block
  int tid = threadIdx.x;
  int l = tid & 63, wid = tid >> 6;
  int ml = l & 31, hi = l >> 5;
  int l8 = l * 8;
  int qh = wid & 1, kh = wid >> 1;
  int q0 = bq0 + qh * 32;

  const size_t tbase = ((size_t)b << 12) * 128;   // b*4096*128
  const unsigned short* pS = phiS + (size_t)b * 524288;
  const unsigned short* vSb = vS + (size_t)b * 524288;

  // Q fragments (B-operand): k map = kc*16 + 8*hi + e
  Frag qf[8];
#pragma unroll
  for (int kc = 0; kc < 8; ++kc)
    qf[kc].u = *(const ushort8*)(theta + tbase +
        (size_t)(q0 + ml) * 128 + kc * 16 + 8 * hi);

  f32x16 oacc[4];                     // 4 d-blocks of 32
#pragma unroll
  for (int db = 0; db < 4; ++db) oacc[db] = fz16();
  float m = -1e30f, sden = 0.f;

  int t0 = kh * 64;                   // wave's kv half: 64 tiles

  Frag pa[8];
#pragma unroll
  for (int kc = 0; kc < 8; ++kc)
    pa[kc].u = *(const ushort8*)(pS + (size_t)t0 * 4096 + kc * 512 + l8);

  for (int kt = 0; kt < 64; ++kt) {
    int t = t0 + kt;

    // S^T[kv 32][q 32] over K=128
    __builtin_amdgcn_s_setprio(1);
    f32x16 sacc = fz16();
#pragma unroll
    for (int kc = 0; kc < 8; ++kc) sacc = MFMA32(pa[kc].b, qf[kc].b, sacc);
    __builtin_amdgcn_s_setprio(0);

    // issue V loads now (consumed after softmax) -- shared with partner wave via L1
    Frag vt[8];
#pragma unroll
    for (int t8 = 0; t8 < 8; ++t8)
      vt[t8].u = *(const ushort8*)(vSb + (size_t)t * 4096 + t8 * 512 + l8);

    // prefetch next tile's phi (affine; tail load dead but mapped)
#pragma unroll
    for (int kc = 0; kc < 8; ++kc)
      pa[kc].u = *(const ushort8*)(pS + (size_t)(t + 1) * 4096 + kc * 512 + l8);

    // ---- in-register softmax (exp2 domain; lane owns q-row, partner l^32) ----
    float m8[8];
#pragma unroll
    for (int j = 0; j < 8; ++j) m8[j] = fmaxf(sacc[j], sacc[j + 8]);
    float t1 = fmaxf(fmaxf(m8[0], m8[1]), m8[2]);
    float t2 = fmaxf(fmaxf(m8[3], m8[4]), m8[5]);
    float t3 = fmaxf(m8[6], m8[7]);
    float mt = fmaxf(fmaxf(t1, t2), t3);
    mt = fmaxf(mt, __shfl_xor(mt, 32));
    if (!__all(mt <= m + 24.0f)) {       // defer-rescale, wide threshold
      float mn = fmaxf(m, mt);
      float sc = __builtin_exp2f(m - mn);
      sden *= sc;
#pragma unroll
      for (int db = 0; db < 4; ++db) oacc[db] *= sc;
      m = mn;
    }
    float p[16];
#pragma unroll
    for (int r = 0; r < 16; ++r) p[r] = __builtin_exp2f(sacc[r] - m);
    float s8[8];
#pragma unroll
    for (int j = 0; j < 8; ++j) s8[j] = p[j] + p[j + 8];
    float ps = ((s8[0] + s8[1]) + (s8[2] + s8[3])) + ((s8[4] + s8[5]) + (s8[6] + s8[7]));
    ps += __shfl_xor(ps, 32);
    sden += ps;

    // pack P to bf16x2 by truncation (P>=0; <=1 ulp vs RNE)
    unsigned wpk[8], pw[8];
#pragma unroll
    for (int j = 0; j < 8; ++j) {
      unsigned u0 = __float_as_uint(p[2 * j]);
      unsigned u1 = __float_as_uint(p[2 * j + 1]);
      wpk[j] = (u1 & 0xFFFF0000u) | (u0 >> 16);
    }
#pragma unroll
    for (int j = 0; j < 8; ++j) pw[j] = (unsigned)__shfl_xor((int)wpk[j], 32);
    // B-frag k map = ks*16 + 8*hi + e
    Frag bf0, bf1;
    bf0.w[0] = hi ? pw[2] : wpk[0];
    bf0.w[1] = hi ? pw[3] : wpk[1];
    bf0.w[2] = hi ? wpk[2] : pw[0];
    bf0.w[3] = hi ? wpk[3] : pw[1];
    bf1.w[0] = hi ? pw[6] : wpk[4];
    bf1.w[1] = hi ? pw[7] : wpk[5];
    bf1.w[2] = hi ? wpk[6] : pw[4];
    bf1.w[3] = hi ? wpk[7] : pw[5];

    // O^T[d][q] += V^T x P
    __builtin_amdgcn_s_setprio(1);
#pragma unroll
    for (int db = 0; db < 4; ++db) {
      oacc[db] = MFMA32(vt[db * 2].b, bf0.b, oacc[db]);
      oacc[db] = MFMA32(vt[db * 2 + 1].b, bf1.b, oacc[db]);
    }
    __builtin_amdgcn_s_setprio(0);
  }

  // ---- 2-way LSE merge: (qh, kh=0) + (qh, kh=1) ----
  if (l < 32) { mls[wid][l][0] = m; mls[wid][l][1] = sden; }
  __syncthreads();
  {
    float M = fmaxf(mls[qh][ml][0], mls[qh + 2][ml][0]);
    float sc = __builtin_exp2f(m - M);
    int orow = qh * 32 + ml;
    if (kh == 0) {
#pragma unroll
      for (int db = 0; db < 4; ++db)
#pragma unroll
        for (int r = 0; r < 16; ++r) {
          int d = db * 32 + (r & 3) + 8 * (r >> 2) + 4 * hi;
          osum[orow][d] = oacc[db][r] * sc;
        }
    }
    __syncthreads();
    if (kh == 1) {
#pragma unroll
      for (int db = 0; db < 4; ++db)
#pragma unroll
        for (int r = 0; r < 16; ++r) {
          int d = db * 32 + (r & 3) + 8 * (r >> 2) + 4 * hi;
          osum[orow][d] += oacc[db][r] * sc;
        }
    }
    __syncthreads();
  }
  // write out SWIZZLED (phiS layout): row = tid&63; chunkpairs wid and wid+4
  {
    int row = tid & 63;
    int mlr = row & 31, qhr = row >> 5;
    int t_ = (bq0 + row) >> 5;
    float Mx = fmaxf(mls[qhr][mlr][0], mls[qhr + 2][mlr][0]);
    float Lt = mls[qhr][mlr][1] * __builtin_exp2f(mls[qhr][mlr][0] - Mx) +
               mls[qhr + 2][mlr][1] * __builtin_exp2f(mls[qhr + 2][mlr][0] - Mx);
    float inv = 1.0f / Lt;
#pragma unroll
    for (int u = 0; u < 2; ++u) {
      int d0 = (wid + 4 * u) * 16;
      ushort8 w1;
      for (int k = 0; k < 8; ++k) w1[k] = f2bf(osum[row][d0 + k] * inv);
      ushort8 w2;
      for (int k = 0; k < 8; ++k) w2[k] = f2bf(osum[row][d0 + 8 + k] * inv);
      size_t a = (size_t)b * 524288 + (size_t)t_ * 4096 +
                 (size_t)(d0 >> 4) * 512 + (size_t)mlr * 8;
      *(ushort8*)(out_nm + a) = w1;         // c = d0+0..7
      *(ushort8*)(out_nm + a + 256) = w2;   // c = d0+8..15
    }
  }
}

// ---------------- mask GEMM + bias + relu + residual (fp32 out) --------------
__global__ __launch_bounds__(256, 2) void k_mask(
    const unsigned short* __restrict__ wmbS, const unsigned short* __restrict__ out_nm,
    const float* __restrict__ bm, const float* __restrict__ x,
    float* __restrict__ out) {
  __shared__ float sout[256 * 68];            // [channel][pos], stride 68
  int gb = blockIdx.x >> 6;
  size_t boff = (size_t)gb * 524288;
  int n0 = (blockIdx.x & 63) << 6;
  int tid = threadIdx.x;
  int l = tid & 63, w = tid >> 6, lr = l & 15, lg = l >> 4;
  int l8 = l * 8;
  f32x4 acc[4][4];
  for (int i = 0; i < 4; ++i) for (int j = 0; j < 4; ++j) acc[i][j] = fz4();
  for (int kc = 0; kc < 4; ++kc) {
    int kc2 = kc * 2 + (lg >> 1), hi2 = lg & 1;
    Frag wa[4], xq[4];
    for (int ot = 0; ot < 4; ++ot)
      wa[ot].u = *(const ushort8*)(wmbS + ((w * 4 + ot) * 4 + kc) * 512 + l8);
    for (int nt = 0; nt < 4; ++nt) {
      int t = (n0 >> 5) + (nt >> 1);
      int mln = ((nt & 1) << 4) + lr;
      xq[nt].u = *(const ushort8*)(out_nm + boff + (size_t)t * 4096 +
                                   (size_t)kc2 * 512 + (size_t)(hi2 * 32 + mln) * 8);
    }
    for (int ot = 0; ot < 4; ++ot)
      for (int nt = 0; nt < 4; ++nt)
        acc[ot][nt] = MFMA16(wa[ot].b, xq[nt].b, acc[ot][nt]);
  }
  // bias + relu into LDS (2-way bank pattern: free)
  for (int ot = 0; ot < 4; ++ot) {
    int o0 = w * 64 + ot * 16 + 4 * lg;
    for (int nt = 0; nt < 4; ++nt) {
      int nn = nt * 16 + lr;
      for (int j = 0; j < 4; ++j) {
        float v = acc[ot][nt][j] + bm[o0 + j];
        sout[(o0 + j) * 68 + nn] = v > 0.f ? v : 0.f;
      }
    }
  }
  __syncthreads();
  // coalesced residual + store: 4096 f32x4 chunks, 16 per thread
  const float* xb = x + (size_t)(gb << 8) * 4096 + n0;
  float* ob = out + (size_t)(gb << 8) * 4096 + n0;
  for (int i = 0; i < 16; ++i) {
    int c = i * 256 + tid;
    int ch = c >> 4, pq = (c & 15) * 4;
    f32x4 xv = *(const f32x4*)(xb + (size_t)ch * 4096 + pq);
    f32x4 sv = *(const f32x4*)&sout[ch * 68 + pq];
    f32x4 ov;
    for (int k = 0; k < 4; ++k) ov[k] = sv[k] + xv[k];
    *(f32x4*)(ob + (size_t)ch * 4096 + pq) = ov;
  }
}

extern "C" void kernel_launch(void* const* d_in, const int* in_sizes, int n_in,
                              void* d_out, int out_size, void* d_ws, size_t ws_size,
                              hipStream_t stream) {
  const float* x  = (const float*)d_in[0];
  const float* wg = (const float*)d_in[1];
  const float* bg = (const float*)d_in[2];
  const float* wt = (const float*)d_in[3];
  const float* bt = (const float*)d_in[4];
  const float* wp = (const float*)d_in[5];
  const float* bp = (const float*)d_in[6];
  const float* wm = (const float*)d_in[7];
  const float* bm = (const float*)d_in[8];
  float* out = (float*)d_out;           // fp32 output

  const size_t SLAB = 524288;           // ushorts per batch slab (1 MB)
  unsigned short* wcatS = (unsigned short*)d_ws;
  unsigned short* wmbS  = wcatS + 98304;
  unsigned short* theta = wmbS + 32768;
  unsigned short* phiS  = theta + 8 * SLAB;
  unsigned short* vS    = phiS + 8 * SLAB;

  k_prep<<<384, 256, 0, stream>>>(wg, wt, wp, wm, wcatS, wmbS);
  k_proj<<<512, 256, 0, stream>>>(x, wcatS, bt, bp, bg, theta, phiS, vS);
  k_attn<<<512, 256, 0, stream>>>(theta, phiS, vS, theta /*alias: out_nm*/);
  k_mask<<<512, 256, 0, stream>>>(wmbS, theta, bm, x, out);
}

// Round 21
// 150.599 us; speedup vs baseline: 1.0086x; 1.0086x over previous
//
#include <hip/hip_runtime.h>

// ---- types ----
typedef __bf16 bf16x8 __attribute__((ext_vector_type(8)));
typedef float f32x4 __attribute__((ext_vector_type(4)));
typedef float f32x16 __attribute__((ext_vector_type(16)));
typedef unsigned short ushort8 __attribute__((ext_vector_type(8)));
typedef unsigned short ushort4v __attribute__((ext_vector_type(4)));
typedef unsigned int uint4v __attribute__((ext_vector_type(4)));

union Frag {
  ushort8 u;
  bf16x8 b;
  uint4v w;
};

__device__ __forceinline__ unsigned short f2bf(float f) {
  unsigned int u = __float_as_uint(f);
  u += 0x7fffu + ((u >> 16) & 1u);   // RNE; inputs are finite
  return (unsigned short)(u >> 16);
}

__device__ __forceinline__ f32x4 fz4() {
  f32x4 v; v[0] = 0.f; v[1] = 0.f; v[2] = 0.f; v[3] = 0.f; return v;
}

__device__ __forceinline__ f32x16 fz16() {
  f32x16 v;
#pragma unroll
  for (int i = 0; i < 16; ++i) v[i] = 0.f;
  return v;
}

#define MFMA16(a, b, c) __builtin_amdgcn_mfma_f32_16x16x32_bf16(a, b, c, 0, 0, 0)
#define MFMA32(a, b, c) __builtin_amdgcn_mfma_f32_32x32x16_bf16(a, b, c, 0, 0, 0)

#define LOG2E 1.4426950408889634f

// Sizes: B=8, C=256, N=4096 (64x64), IC=128. OUTPUT FP32 (32 MiB).
// ws (ushort): wcatS 98304 | wmbS 32768 | theta 8*524288 | phiS 8*524288 | vS 8*524288
// theta: linear [n][128], PRE-SCALED by log2(e)  (softmax runs in exp2 domain)
// phiS swizzled (per batch): addr = t*4096 + kc*512 + lane*8 + e
// vS swizzled (per batch):  addr = t*4096 + t8*512 + lane*8 + e
// wcatS fragment-swizzled: element (row,col) -> ((row>>4)*8 + (col>>5))*512 +
//   (((col>>3)&3)*16 + (row&15))*8 + (col&7)    [rows 0-127 wt | 128-255 wp | 256-383 wg]
// wmbS  fragment-swizzled: ((row>>4)*4 + (col>>5))*512 + (((col>>3)&3)*16+(row&15))*8+(col&7)
// -> every weight fragment load is a 64-lane contiguous 1KB burst.
// attn output out_nm (aliases theta): phiS-style swizzle -> k_mask coalesced.

// ---------------- prep: weights fp32 -> bf16, fragment-swizzled --------------
__global__ void k_prep(const float* __restrict__ wg, const float* __restrict__ wt,
                       const float* __restrict__ wp, const float* __restrict__ wm,
                       unsigned short* __restrict__ wcatS, unsigned short* __restrict__ wmbS) {
  int t = blockIdx.x * 256 + threadIdx.x;
  if (t < 98304) {
    int row = t >> 8, col = t & 255;
    const float* src = (row < 128) ? wt : ((row < 256) ? wp : wg);
    unsigned short v = f2bf(src[(row & 127) * 256 + col]);
    int R = row >> 4, lr = row & 15, kc = col >> 5, lg = (col >> 3) & 3, e = col & 7;
    wcatS[((R * 8 + kc) * 64 + lg * 16 + lr) * 8 + e] = v;
  }
  if (t < 32768) {
    int row = t >> 7, col = t & 127;
    unsigned short v = f2bf(wm[t]);
    int R = row >> 4, lr = row & 15, kc = col >> 5, lg = (col >> 3) & 3, e = col & 7;
    wmbS[((R * 4 + kc) * 64 + lg * 16 + lr) * 8 + e] = v;
  }
}

// ---- shared staging: x[bx][c][pt0..pt0+64) -> xb[p][c] bf16, row stride 264 ----
__device__ __forceinline__ void stage_x(const float* __restrict__ x, int bx, int pt0,
                                        unsigned short* xb, int tid) {
  int c0 = (tid >> 2) * 4;
  int psub = (tid & 3) * 16;
  const float* xbase = x + (size_t)bx * 256 * 4096 + pt0;
  for (int ppc = 0; ppc < 4; ++ppc) {
    int p0 = psub + ppc * 4;
    f32x4 r0 = *(const f32x4*)(xbase + (size_t)(c0 + 0) * 4096 + p0);
    f32x4 r1 = *(const f32x4*)(xbase + (size_t)(c0 + 1) * 4096 + p0);
    f32x4 r2 = *(const f32x4*)(xbase + (size_t)(c0 + 2) * 4096 + p0);
    f32x4 r3 = *(const f32x4*)(xbase + (size_t)(c0 + 3) * 4096 + p0);
    for (int e = 0; e < 4; ++e) {
      ushort4v wv;
      wv[0] = f2bf(r0[e]); wv[1] = f2bf(r1[e]); wv[2] = f2bf(r2[e]); wv[3] = f2bf(r3[e]);
      *(ushort4v*)&xb[(p0 + e) * 264 + c0] = wv;
    }
  }
}

// ---------------- fused projections: theta (scaled), phiS, vS ----------------
__global__ __launch_bounds__(256, 2) void k_proj(
    const float* __restrict__ x, const unsigned short* __restrict__ wcatS,
    const float* __restrict__ bt, const float* __restrict__ bp,
    const float* __restrict__ bg,
    unsigned short* __restrict__ theta, unsigned short* __restrict__ phiS,
    unsigned short* __restrict__ vS) {
  __shared__ unsigned short xb[64 * 264];
  int gb = blockIdx.x >> 6;
  size_t ob_off = (size_t)gb * 524288;
  int pt0 = (blockIdx.x & 63) << 6;
  int tid = threadIdx.x;
  stage_x(x, gb, pt0, xb, tid);
  __syncthreads();
  int l = tid & 63, w = tid >> 6, lr = l & 15, lg = l >> 4;
  int l8 = l * 8;
  int obase = w * 64;
  f32x4 acc[4][4];
  f32x4 accg[8];
  for (int i = 0; i < 4; ++i) for (int j = 0; j < 4; ++j) acc[i][j] = fz4();
  for (int i = 0; i < 8; ++i) accg[i] = fz4();
  for (int kc = 0; kc < 8; ++kc) {
    int ko = kc * 32 + 8 * lg;
    Frag wa[4], xq[4];
    for (int ot = 0; ot < 4; ++ot)
      wa[ot].u = *(const ushort8*)(wcatS + ((w * 4 + ot) * 8 + kc) * 512 + l8);
    for (int pt = 0; pt < 4; ++pt)
      xq[pt].u = *(const ushort8*)&xb[(pt * 16 + lr) * 264 + ko];
    for (int ot = 0; ot < 4; ++ot)
      for (int pt = 0; pt < 4; ++pt)
        acc[ot][pt] = MFMA16(wa[ot].b, xq[pt].b, acc[ot][pt]);
    for (int ot = 0; ot < 8; ++ot) {
      Frag wb;
      wb.u = *(const ushort8*)(wcatS + ((16 + ot) * 8 + kc) * 512 + l8);
      accg[ot] = MFMA16(xq[w].b, wb.b, accg[ot]);
    }
  }
  // epilogue theta/phi
  for (int ot = 0; ot < 4; ++ot) {
    int o0 = obase + ot * 16 + 4 * lg;
    float bias[4];
    for (int j = 0; j < 4; ++j) bias[j] = (o0 < 128) ? bt[o0 + j] : bp[o0 + j - 128];
    for (int pt = 0; pt < 4; ++pt) {
      int n = pt0 + pt * 16 + lr;
      ushort4v wv;
      if (o0 < 128) {
        for (int j = 0; j < 4; ++j) {
          float v = acc[ot][pt][j] + bias[j];
          wv[j] = f2bf(v > 0.f ? v * LOG2E : 0.f);   // exp2-domain Q
        }
        *(ushort4v*)(theta + ob_off + (size_t)n * 128 + o0) = wv;
      } else {
        for (int j = 0; j < 4; ++j) {
          float v = acc[ot][pt][j] + bias[j];
          wv[j] = f2bf(v > 0.f ? v : 0.f);
        }
        int oc = o0 - 128;
        size_t a = (size_t)(n >> 5) * 4096 + (size_t)(oc >> 4) * 512 +
                   (size_t)((oc >> 3) & 1) * 256 + (size_t)(n & 31) * 8 + (oc & 7);
        *(ushort4v*)(phiS + ob_off + a) = wv;
      }
    }
  }
  // epilogue g
  for (int ot = 0; ot < 8; ++ot) {
    int o = ot * 16 + lr;
    float bias = bg[o];
    int n0 = pt0 + w * 16 + 4 * lg;
    ushort4v wv;
    for (int j = 0; j < 4; ++j) {
      float v = accg[ot][j] + bias;
      wv[j] = f2bf(v > 0.f ? v : 0.f);
    }
    size_t a = (size_t)(n0 >> 5) * 4096 +
               (size_t)((o >> 5) * 2 + ((n0 >> 4) & 1)) * 512 +
               (size_t)((((n0 >> 3) & 1) << 5) | (o & 31)) * 8 + (n0 & 7);
    *(ushort4v*)(vS + ob_off + a) = wv;
  }
}

// ---------------- fused flash attention (r14/r19 structure, best: 106.4 us) --
__global__ __launch_bounds__(256, 2) void k_attn(
    const unsigned short* __restrict__ theta, const unsigned short* __restrict__ phiS,
    const unsigned short* __restrict__ vS, unsigned short* __restrict__ out_nm) {
  __shared__ float osum[64][132];
  __shared__ float mls[4][32][2];
  int bid = blockIdx.x;
  int b = bid & 7;                    // XCD-aware: batch per XCD
  int bq0 = (bid >> 3) << 6;          // 64 q-rows per block
  int tid = threadIdx.x;
  int l = tid & 63, wid = tid >> 6;
  int ml = l & 31, hi = l >> 5;
  int l8 = l * 8;
  int qh = wid & 1, kh = wid >> 1;
  int q0 = bq0 + qh * 32;

  const size_t tbase = ((size_t)b << 12) * 128;   // b*4096*128
  const unsigned short* pS = phiS + (size_t)b * 524288;
  const unsigned short* vSb = vS + (size_t)b * 524288;

  // Q fragments (B-operand): k map = kc*16 + 8*hi + e
  Frag qf[8];
#pragma unroll
  for (int kc = 0; kc < 8; ++kc)
    qf[kc].u = *(const ushort8*)(theta + tbase +
        (size_t)(q0 + ml) * 128 + kc * 16 + 8 * hi);

  f32x16 oacc[4];                     // 4 d-blocks of 32
#pragma unroll
  for (int db = 0; db < 4; ++db) oacc[db] = fz16();
  float m = -1e30f, sden = 0.f;

  int t0 = kh * 64;                   // wave's kv half: 64 tiles

  Frag pa[8];
#pragma unroll
  for (int kc = 0; kc < 8; ++kc)
    pa[kc].u = *(const ushort8*)(pS + (size_t)t0 * 4096 + kc * 512 + l8);

  for (int kt = 0; kt < 64; ++kt) {
    int t = t0 + kt;

    // S^T[kv 32][q 32] over K=128
    f32x16 sacc = fz16();
#pragma unroll
    for (int kc = 0; kc < 8; ++kc) sacc = MFMA32(pa[kc].b, qf[kc].b, sacc);

    // issue V loads now (consumed after softmax) -- shared with partner wave via L1
    Frag vt[8];
#pragma unroll
    for (int t8 = 0; t8 < 8; ++t8)
      vt[t8].u = *(const ushort8*)(vSb + (size_t)t * 4096 + t8 * 512 + l8);

    // prefetch next tile's phi (affine; tail load dead but mapped)
#pragma unroll
    for (int kc = 0; kc < 8; ++kc)
      pa[kc].u = *(const ushort8*)(pS + (size_t)(t + 1) * 4096 + kc * 512 + l8);

    // ---- in-register softmax (exp2 domain; lane owns q-row, partner l^32) ----
    float m8[8];
#pragma unroll
    for (int j = 0; j < 8; ++j) m8[j] = fmaxf(sacc[j], sacc[j + 8]);
    float t1 = fmaxf(fmaxf(m8[0], m8[1]), m8[2]);
    float t2 = fmaxf(fmaxf(m8[3], m8[4]), m8[5]);
    float t3 = fmaxf(m8[6], m8[7]);
    float mt = fmaxf(fmaxf(t1, t2), t3);
    mt = fmaxf(mt, __shfl_xor(mt, 32));
    if (!__all(mt <= m + 24.0f)) {       // defer-rescale, wide threshold
      float mn = fmaxf(m, mt);
      float sc = __builtin_exp2f(m - mn);
      sden *= sc;
#pragma unroll
      for (int db = 0; db < 4; ++db) oacc[db] *= sc;
      m = mn;
    }
    float p[16];
#pragma unroll
    for (int r = 0; r < 16; ++r) p[r] = __builtin_exp2f(sacc[r] - m);
    float s8[8];
#pragma unroll
    for (int j = 0; j < 8; ++j) s8[j] = p[j] + p[j + 8];
    float ps = ((s8[0] + s8[1]) + (s8[2] + s8[3])) + ((s8[4] + s8[5]) + (s8[6] + s8[7]));
    ps += __shfl_xor(ps, 32);
    sden += ps;

    // pack P to bf16x2 by truncation (P>=0; <=1 ulp vs RNE)
    unsigned wpk[8], pw[8];
#pragma unroll
    for (int j = 0; j < 8; ++j) {
      unsigned u0 = __float_as_uint(p[2 * j]);
      unsigned u1 = __float_as_uint(p[2 * j + 1]);
      wpk[j] = (u1 & 0xFFFF0000u) | (u0 >> 16);
    }
#pragma unroll
    for (int j = 0; j < 8; ++j) pw[j] = (unsigned)__shfl_xor((int)wpk[j], 32);
    // B-frag k map = ks*16 + 8*hi + e
    Frag bf0, bf1;
    bf0.w[0] = hi ? pw[2] : wpk[0];
    bf0.w[1] = hi ? pw[3] : wpk[1];
    bf0.w[2] = hi ? wpk[2] : pw[0];
    bf0.w[3] = hi ? wpk[3] : pw[1];
    bf1.w[0] = hi ? pw[6] : wpk[4];
    bf1.w[1] = hi ? pw[7] : wpk[5];
    bf1.w[2] = hi ? wpk[6] : pw[4];
    bf1.w[3] = hi ? wpk[7] : pw[5];

    // O^T[d][q] += V^T x P
#pragma unroll
    for (int db = 0; db < 4; ++db) {
      oacc[db] = MFMA32(vt[db * 2].b, bf0.b, oacc[db]);
      oacc[db] = MFMA32(vt[db * 2 + 1].b, bf1.b, oacc[db]);
    }
  }

  // ---- 2-way LSE merge: (qh, kh=0) + (qh, kh=1) ----
  if (l < 32) { mls[wid][l][0] = m; mls[wid][l][1] = sden; }
  __syncthreads();
  {
    float M = fmaxf(mls[qh][ml][0], mls[qh + 2][ml][0]);
    float sc = __builtin_exp2f(m - M);
    int orow = qh * 32 + ml;
    if (kh == 0) {
#pragma unroll
      for (int db = 0; db < 4; ++db)
#pragma unroll
        for (int r = 0; r < 16; ++r) {
          int d = db * 32 + (r & 3) + 8 * (r >> 2) + 4 * hi;
          osum[orow][d] = oacc[db][r] * sc;
        }
    }
    __syncthreads();
    if (kh == 1) {
#pragma unroll
      for (int db = 0; db < 4; ++db)
#pragma unroll
        for (int r = 0; r < 16; ++r) {
          int d = db * 32 + (r & 3) + 8 * (r >> 2) + 4 * hi;
          osum[orow][d] += oacc[db][r] * sc;
        }
    }
    __syncthreads();
  }
  // write out SWIZZLED (phiS layout): row = tid&63; chunkpairs wid and wid+4
  {
    int row = tid & 63;
    int mlr = row & 31, qhr = row >> 5;
    int t_ = (bq0 + row) >> 5;
    float Mx = fmaxf(mls[qhr][mlr][0], mls[qhr + 2][mlr][0]);
    float Lt = mls[qhr][mlr][1] * __builtin_exp2f(mls[qhr][mlr][0] - Mx) +
               mls[qhr + 2][mlr][1] * __builtin_exp2f(mls[qhr + 2][mlr][0] - Mx);
    float inv = 1.0f / Lt;
#pragma unroll
    for (int u = 0; u < 2; ++u) {
      int d0 = (wid + 4 * u) * 16;
      ushort8 w1;
      for (int k = 0; k < 8; ++k) w1[k] = f2bf(osum[row][d0 + k] * inv);
      ushort8 w2;
      for (int k = 0; k < 8; ++k) w2[k] = f2bf(osum[row][d0 + 8 + k] * inv);
      size_t a = (size_t)b * 524288 + (size_t)t_ * 4096 +
                 (size_t)(d0 >> 4) * 512 + (size_t)mlr * 8;
      *(ushort8*)(out_nm + a) = w1;         // c = d0+0..7
      *(ushort8*)(out_nm + a + 256) = w2;   // c = d0+8..15
    }
  }
}

// ---------------- mask GEMM + bias + relu + residual (fp32 out) --------------
// Weights from wmbS (coalesced 1KB fragment bursts); C routed through LDS so
// the out-write and x-read are fully coalesced f32x4 chunks.
__global__ __launch_bounds__(256, 2) void k_mask(
    const unsigned short* __restrict__ wmbS, const unsigned short* __restrict__ out_nm,
    const float* __restrict__ bm, const float* __restrict__ x,
    float* __restrict__ out) {
  __shared__ float sout[256 * 68];            // [channel][pos], stride 68
  int gb = blockIdx.x >> 6;
  size_t boff = (size_t)gb * 524288;
  int n0 = (blockIdx.x & 63) << 6;
  int tid = threadIdx.x;
  int l = tid & 63, w = tid >> 6, lr = l & 15, lg = l >> 4;
  int l8 = l * 8;
  f32x4 acc[4][4];
  for (int i = 0; i < 4; ++i) for (int j = 0; j < 4; ++j) acc[i][j] = fz4();
  for (int kc = 0; kc < 4; ++kc) {
    int kc2 = kc * 2 + (lg >> 1), hi2 = lg & 1;
    Frag wa[4], xq[4];
    for (int ot = 0; ot < 4; ++ot)
      wa[ot].u = *(const ushort8*)(wmbS + ((w * 4 + ot) * 4 + kc) * 512 + l8);
    for (int nt = 0; nt < 4; ++nt) {
      int t = (n0 >> 5) + (nt >> 1);
      int mln = ((nt & 1) << 4) + lr;
      xq[nt].u = *(const ushort8*)(out_nm + boff + (size_t)t * 4096 +
                                   (size_t)kc2 * 512 + (size_t)(hi2 * 32 + mln) * 8);
    }
    for (int ot = 0; ot < 4; ++ot)
      for (int nt = 0; nt < 4; ++nt)
        acc[ot][nt] = MFMA16(wa[ot].b, xq[nt].b, acc[ot][nt]);
  }
  // bias + relu into LDS (2-way bank pattern: free)
  for (int ot = 0; ot < 4; ++ot) {
    int o0 = w * 64 + ot * 16 + 4 * lg;
    for (int nt = 0; nt < 4; ++nt) {
      int nn = nt * 16 + lr;
      for (int j = 0; j < 4; ++j) {
        float v = acc[ot][nt][j] + bm[o0 + j];
        sout[(o0 + j) * 68 + nn] = v > 0.f ? v : 0.f;
      }
    }
  }
  __syncthreads();
  // coalesced residual + store: 4096 f32x4 chunks, 16 per thread
  const float* xb = x + (size_t)(gb << 8) * 4096 + n0;
  float* ob = out + (size_t)(gb << 8) * 4096 + n0;
  for (int i = 0; i < 16; ++i) {
    int c = i * 256 + tid;
    int ch = c >> 4, pq = (c & 15) * 4;
    f32x4 xv = *(const f32x4*)(xb + (size_t)ch * 4096 + pq);
    f32x4 sv = *(const f32x4*)&sout[ch * 68 + pq];
    f32x4 ov;
    for (int k = 0; k < 4; ++k) ov[k] = sv[k] + xv[k];
    *(f32x4*)(ob + (size_t)ch * 4096 + pq) = ov;
  }
}

extern "C" void kernel_launch(void* const* d_in, const int* in_sizes, int n_in,
                              void* d_out, int out_size, void* d_ws, size_t ws_size,
                              hipStream_t stream) {
  const float* x  = (const float*)d_in[0];
  const float* wg = (const float*)d_in[1];
  const float* bg = (const float*)d_in[2];
  const float* wt = (const float*)d_in[3];
  const float* bt = (const float*)d_in[4];
  const float* wp = (const float*)d_in[5];
  const float* bp = (const float*)d_in[6];
  const float* wm = (const float*)d_in[7];
  const float* bm = (const float*)d_in[8];
  float* out = (float*)d_out;           // fp32 output

  const size_t SLAB = 524288;           // ushorts per batch slab (1 MB)
  unsigned short* wcatS = (unsigned short*)d_ws;
  unsigned short* wmbS  = wcatS + 98304;
  unsigned short* theta = wmbS + 32768;
  unsigned short* phiS  = theta + 8 * SLAB;
  unsigned short* vS    = phiS + 8 * SLAB;

  k_prep<<<384, 256, 0, stream>>>(wg, wt, wp, wm, wcatS, wmbS);
  k_proj<<<512, 256, 0, stream>>>(x, wcatS, bt, bp, bg, theta, phiS, vS);
  k_attn<<<512, 256, 0, stream>>>(theta, phiS, vS, theta /*alias: out_nm*/);
  k_mask<<<512, 256, 0, stream>>>(wmbS, theta, bm, x, out);
}